// Round 5
// baseline (2054.235 us; speedup 1.0000x reference)
//
#include <hip/hip_runtime.h>
#include <stdint.h>

// ============================================================================
// CPM layer, bit-exact JAX reproduction. B=8, C=8, H=W=1024.
// Round 5: single persistent cooperative-style kernel (manual grid barrier,
// device-scope atomics + threadfence, monotonic counter). Phases:
//   prep (LDS-repacked parity-packed dHNN writes) | 8x (copy slice + half
//   step) | finalize. RNG / dot-product / exp bit-identical to passing rounds.
// ============================================================================

#define HW    1048576    // 1024*1024
#define BHWu  8388608u   // 8*HW
#define NHu   4194304u   // BHW/2 = packed entries per parity
#define ROWS  8192       // b*1024+y
#define CPS   1835008u   // ch1-7 copy float4 per step (14,680,064 / 8)

struct Keys8 { uint32_t k[8][4]; };   // dk0,dk1,uk0,uk1 per step

// ---------------------------------------------------------------------- RNG
__device__ __host__ __forceinline__ void tf2x32(uint32_t k0, uint32_t k1,
                                                uint32_t x0, uint32_t x1,
                                                uint32_t& o0, uint32_t& o1) {
  uint32_t k2 = k0 ^ k1 ^ 0x1BD11BDAu;
  x0 += k0; x1 += k1;
#define RDD(r) { x0 += x1; x1 = (x1 << (r)) | (x1 >> (32 - (r))); x1 ^= x0; }
  RDD(13) RDD(15) RDD(26) RDD(6)
  x0 += k1; x1 += k2 + 1u;
  RDD(17) RDD(29) RDD(16) RDD(24)
  x0 += k2; x1 += k0 + 2u;
  RDD(13) RDD(15) RDD(26) RDD(6)
  x0 += k0; x1 += k1 + 3u;
  RDD(17) RDD(29) RDD(16) RDD(24)
  x0 += k1; x1 += k2 + 4u;
  RDD(13) RDD(15) RDD(26) RDD(6)
  x0 += k2; x1 += k0 + 5u;
#undef RDD
  o0 = x0; o1 = x1;
}

// ------------------------------------------------- XLA-CPU Cephes expf clone
__device__ __forceinline__ float xla_expf(float input) {
  float x  = fmaxf(fminf(input, 88.3762626647950f), -88.3762626647949f);
  float fx = floorf(fmaf(x, 1.44269504088896341f, 0.5f));
  float tmp = __fmul_rn(0.693359375f, fx);
  float z   = __fmul_rn(-2.12194440e-4f, fx);
  x = __fsub_rn(x, tmp);
  x = __fsub_rn(x, z);
  z = __fmul_rn(x, x);
  float y = fmaf(x, 1.9875691500e-4f, 1.3981999507e-3f);
  y = fmaf(y, x, 8.3334519073e-3f);
  y = fmaf(y, x, 4.1665795894e-2f);
  y = fmaf(y, x, 1.6666665459e-1f);
  y = fmaf(y, x, 5.0000001201e-1f);
  y = fmaf(y, z, x);
  y = __fadd_rn(y, 1.0f);
  int n = (int)fx;
  float p2n = __int_as_float((n + 127) << 23);
  return fmaxf(__fmul_rn(y, p2n), input);
}

// ----------------------------------------------------------- Metropolis core
__device__ __forceinline__ void metro_one(uint32_t u, uint32_t sub,
                                          uint8_t* __restrict__ ids,
                                          const float* __restrict__ dHNN,
                                          uint32_t dk0, uint32_t dk1,
                                          uint32_t uk0, uint32_t uk1) {
  uint32_t b = u >> 19;
  uint32_t r = u & 524287u;
  uint32_t y = r >> 9;
  uint32_t i = r & 511u;
  uint32_t x = (i << 1) | ((y + sub) & 1u);     // (y+x)%2 == sub
  uint32_t p = (b << 20) | (y << 10) | x;

  float4 dnn = ((const float4*)dHNN)[sub * NHu + u];

  uint32_t d0, d1, u0, u1;
  tf2x32(dk0, dk1, 0u, p, d0, d1);              // randint lower_bits
  uint32_t db = d0 ^ d1;
  tf2x32(uk0, uk1, 0u, p, u0, u1);              // uniform bits
  uint32_t ub = u0 ^ u1;
  int   dir = (int)(db & 3u);
  float uu  = __fsub_rn(__uint_as_float((ub >> 9) | 0x3F800000u), 1.0f);

  uint32_t yN = (y + 1) & 1023u, yP = (y - 1) & 1023u;
  uint32_t xN = (x + 1) & 1023u, xP = (x - 1) & 1023u;
  uint32_t base = b << 20;
  uint32_t c  = ids[p];
  uint32_t n0 = ids[base + (yN << 10) + x];     // roll(-1,0)
  uint32_t n1 = ids[base + (yP << 10) + x];     // roll(+1,0)
  uint32_t n2 = ids[base + (y << 10) + xN];     // roll(0,-1)
  uint32_t n3 = ids[base + (y << 10) + xP];     // roll(0,+1)
  uint32_t s  = (dir == 0) ? n0 : (dir == 1) ? n1 : (dir == 2) ? n2 : n3;
  float dH_nn = (dir == 0) ? dnn.x : (dir == 1) ? dnn.y : (dir == 2) ? dnn.z : dnn.w;
  int dadh = ((int)(n0 != s) + (int)(n1 != s) + (int)(n2 != s) + (int)(n3 != s))
           - ((int)(n0 != c) + (int)(n1 != c) + (int)(n2 != c) + (int)(n3 != c));
  float dH = __fadd_rn((float)dadh, dH_nn);
  if (uu < xla_expf(-dH)) ids[p] = (uint8_t)s;
}

// --------------------------------------------------------- manual grid sync
__device__ __forceinline__ void gridbar(uint32_t* bar, uint32_t target) {
  __syncthreads();
  if (threadIdx.x == 0) {
    __threadfence();                                        // release
    atomicAdd(bar, 1u);                                     // device scope
    while (__hip_atomic_load(bar, __ATOMIC_RELAXED,
                             __HIP_MEMORY_SCOPE_AGENT) < target)
      __builtin_amdgcn_s_sleep(8);
    __threadfence();
  }
  __syncthreads();
  __threadfence();                                          // acquire (all)
}

__global__ void zero_bar(uint32_t* bar) { *bar = 0u; }

// ------------------------------------------------------- persistent kernel
__global__ __launch_bounds__(256) void cpm_coop(const float* __restrict__ X,
                                                const float* __restrict__ W,
                                                const float* __restrict__ Bb,
                                                float* __restrict__ dHNN,
                                                uint8_t* __restrict__ ids,
                                                float* __restrict__ out,
                                                uint32_t* bar, Keys8 K) {
  const int      tid = (int)threadIdx.x;
  const uint32_t gti = blockIdx.x * 256u + (uint32_t)tid;
  const uint32_t NT  = gridDim.x * 256u;
  __shared__ float4 pack[2][512];     // 16 KiB: one row, parity-packed

  // ---- phase P: prep (block-per-row; LDS repack -> coalesced packed writes)
  for (uint32_t row = blockIdx.x; row < ROWS; row += gridDim.x) {
    uint32_t b = row >> 10, y = row & 1023u;
    const float4* xb = (const float4*)(X + ((size_t)b << 23));
    uint32_t fq = (y << 8) + (uint32_t)tid;     // float4 idx within plane
    float4 xc[8];
#pragma unroll
    for (int c = 0; c < 8; c++) xc[c] = xb[((uint32_t)c << 18) + fq];
    uchar4 v;
    v.x = (uint8_t)(int)xc[0].x; v.y = (uint8_t)(int)xc[0].y;
    v.z = (uint8_t)(int)xc[0].z; v.w = (uint8_t)(int)xc[0].w;
    *(uchar4*)(ids + (b << 20) + (y << 10) + 4u * (uint32_t)tid) = v;
#pragma unroll
    for (int j = 0; j < 4; j++) {
      float4 r;
#pragma unroll
      for (int o = 0; o < 4; o++) {
        float acc = 0.0f;
#pragma unroll
        for (int c = 0; c < 8; c++)
          acc = __fadd_rn(acc, __fmul_rn(((const float*)&xc[c])[j], W[o * 8 + c]));
        ((float*)&r)[o] = __fadd_rn(acc, Bb[o]);
      }
      pack[(y + (uint32_t)j) & 1u][(tid << 1) | (j >> 1)] = r;   // slot = xj>>1
    }
    __syncthreads();
    {
      uint32_t qb = (b << 19) | (y << 9);
      float4* d4 = (float4*)dHNN;
      d4[qb + (uint32_t)tid]              = pack[0][tid];
      d4[qb + (uint32_t)tid + 256u]       = pack[0][tid + 256];
      d4[NHu + qb + (uint32_t)tid]        = pack[1][tid];
      d4[NHu + qb + (uint32_t)tid + 256u] = pack[1][tid + 256];
    }
    __syncthreads();
  }

  uint32_t phase = 1;
  gridbar(bar, gridDim.x * phase++);

  // ---- phases H0..H7: copy slice + Metropolis half step
  for (int t = 0; t < 8; t++) {
    for (uint32_t i = gti; i < CPS; i += NT) {          // ch1-7 pass-through
      uint32_t f  = (uint32_t)t * CPS + i;
      uint32_t bc = f >> 18, q4 = f & 262143u;
      uint32_t b  = bc / 7u, c = bc - b * 7u + 1u;
      size_t  off = ((size_t)b << 23) + ((size_t)c << 20);
      ((float4*)(out + off))[q4] = ((const float4*)(X + off))[q4];
    }
    uint32_t sub = (uint32_t)(t & 1);
    uint32_t dk0 = K.k[t][0], dk1 = K.k[t][1], uk0 = K.k[t][2], uk1 = K.k[t][3];
    for (uint32_t u = gti; u < NHu; u += NT)
      metro_one(u, sub, ids, dHNN, dk0, dk1, uk0, uk1);
    gridbar(bar, gridDim.x * phase++);
  }

  // ---- phase F: out channel 0 <- ids
  for (uint32_t i = gti; i < (BHWu >> 2); i += NT) {
    uint32_t e = i << 2, b = e >> 20, yx = e & (HW - 1);
    uchar4 v = *(const uchar4*)(ids + e);
    float4 r;
    r.x = (float)v.x; r.y = (float)v.y; r.z = (float)v.z; r.w = (float)v.w;
    ((float4*)(out + ((size_t)b << 23)))[yx >> 2] = r;
  }
}

// ----------------------------------------------- fallback (small-ws) kernels
__global__ __launch_bounds__(256) void prep4_fb(const float* __restrict__ X,
                                                const float* __restrict__ W,
                                                const float* __restrict__ Bb,
                                                float* __restrict__ dHNN,
                                                uint8_t* __restrict__ ids) {
  int tid = blockIdx.x * 256 + threadIdx.x;
  int e   = tid << 2;
  int b   = e >> 20;
  int yx  = e & (HW - 1);
  int y   = yx >> 10;
  int x0  = yx & 1023;
  int q4  = yx >> 2;
  const float4* xb = (const float4*)(X + ((size_t)b << 23));
  float4 xc[8];
#pragma unroll
  for (int c = 0; c < 8; c++) xc[c] = xb[(c << 18) + q4];
#pragma unroll
  for (int j = 0; j < 4; j++) {
    float4 r;
#pragma unroll
    for (int o = 0; o < 4; o++) {
      float acc = 0.0f;
#pragma unroll
      for (int c = 0; c < 8; c++)
        acc = __fadd_rn(acc, __fmul_rn(((const float*)&xc[c])[j], W[o * 8 + c]));
      ((float*)&r)[o] = __fadd_rn(acc, Bb[o]);
    }
    int xj = x0 + j;
    ((float4*)dHNN)[((xj + y) & 1) * NHu + (uint32_t)((b << 19) | (y << 9) | (xj >> 1))] = r;
  }
  uchar4 v;
  v.x = (uint8_t)(int)xc[0].x; v.y = (uint8_t)(int)xc[0].y;
  v.z = (uint8_t)(int)xc[0].z; v.w = (uint8_t)(int)xc[0].w;
  *(uchar4*)(ids + e) = v;
}

__global__ __launch_bounds__(256) void half_step_fb(uint8_t* __restrict__ ids,
                                                    const float* __restrict__ dHNN,
                                                    uint32_t dk0, uint32_t dk1,
                                                    uint32_t uk0, uint32_t uk1,
                                                    int sub) {
  uint32_t u = blockIdx.x * 256u + threadIdx.x;
  metro_one(u, (uint32_t)sub, ids, dHNN, dk0, dk1, uk0, uk1);
}

__global__ __launch_bounds__(256) void finalize_full_fb(const float* __restrict__ X,
                                                        const uint8_t* __restrict__ ids,
                                                        float* __restrict__ out) {
  int t = blockIdx.x * 256 + threadIdx.x;
  int e = t << 2;
  int c = (e >> 20) & 7;
  float4 r;
  if (c == 0) {
    int b  = e >> 23;
    int yx = e & (HW - 1);
    uchar4 v = *(const uchar4*)(ids + ((size_t)b << 20) + yx);
    r.x = (float)v.x; r.y = (float)v.y; r.z = (float)v.z; r.w = (float)v.w;
  } else {
    r = ((const float4*)X)[t];
  }
  ((float4*)out)[t] = r;
}

// --------------------------------------------------------------------- host
extern "C" void kernel_launch(void* const* d_in, const int* in_sizes, int n_in,
                              void* d_out, int out_size, void* d_ws, size_t ws_size,
                              hipStream_t stream) {
  const float* X  = (const float*)d_in[0];
  const float* W  = (const float*)d_in[1];
  const float* Bb = (const float*)d_in[2];
  float* out = (float*)d_out;

  const size_t DHNN_BYTES = (size_t)BHWu * 16u;       // 134 MB
  const size_t IDS_BYTES  = (size_t)BHWu;             // 8.4 MB
  const size_t BAR_OFF    = DHNN_BYTES + IDS_BYTES;   // counter after ids

  // Threefry key chain (partitionable stream; verified rounds 2-4).
  uint32_t bk0 = 0u, bk1 = 42u;
  uint32_t keys[8][2];
  for (uint32_t t = 0; t < 8; t++)
    tf2x32(bk0, bk1, 0u, t, keys[t][0], keys[t][1]);
  Keys8 K;
  for (int t = 0; t < 8; t++) {
    uint32_t k1a, k1b;
    tf2x32(keys[t][0], keys[t][1], 0u, 0u, k1a, k1b);        // k1
    tf2x32(keys[t][0], keys[t][1], 0u, 1u, K.k[t][2], K.k[t][3]); // k2 -> ukey
    tf2x32(k1a, k1b, 0u, 1u, K.k[t][0], K.k[t][1]);          // randint kk2 -> dkey
  }

  int bpc = 0, ncu = 0, dev = 0;
  hipGetDevice(&dev);
  hipOccupancyMaxActiveBlocksPerMultiprocessor(&bpc, cpm_coop, 256, 0);
  hipDeviceGetAttribute(&ncu, hipDeviceAttributeMultiprocessorCount, dev);
  if (ncu <= 0) ncu = 256;
  bool ws_ok = (ws_size >= BAR_OFF + 256) && (bpc >= 1);

  if (ws_ok) {
    float*    dHNN = (float*)d_ws;
    uint8_t*  ids  = (uint8_t*)d_ws + DHNN_BYTES;
    uint32_t* bar  = (uint32_t*)((uint8_t*)d_ws + BAR_OFF);
    int G = (bpc > 8 ? 8 : bpc) * ncu;                 // guaranteed co-resident
    zero_bar<<<1, 1, 0, stream>>>(bar);
    cpm_coop<<<G, 256, 0, stream>>>(X, W, Bb, dHNN, ids, out, bar, K);
  } else {
    // dHNN lives in out; ids in ws (needs 8.4 MB).
    float*   dHNN = out;
    uint8_t* ids  = (uint8_t*)d_ws;
    prep4_fb<<<8192, 256, 0, stream>>>(X, W, Bb, dHNN, ids);
    for (int t = 0; t < 8; t++)
      half_step_fb<<<16384, 256, 0, stream>>>(ids, dHNN,
          K.k[t][0], K.k[t][1], K.k[t][2], K.k[t][3], t & 1);
    finalize_full_fb<<<65536, 256, 0, stream>>>(X, ids, out);
  }
  (void)in_sizes; (void)n_in; (void)out_size;
}

// Round 6
// 314.252 us; speedup vs baseline: 6.5369x; 6.5369x over previous
//
#include <hip/hip_runtime.h>
#include <stdint.h>

// ============================================================================
// CPM layer, bit-exact JAX reproduction. B=8, C=8, H=W=1024.
// Round 6: back to multi-launch (round-5 coop barrier was preemption-bound).
//   prep_row: block-per-row, LDS parity repack -> coalesced dHNN writes,
//             ch1-7 pass-through fused (write-only cost).
//   half_step4: 4 active px/thread (u64 neighbor loads, amortized addressing).
//   step 7 writes out-ch0 directly (finalize kernel eliminated).
// RNG / dot order / Cephes exp bit-identical to passing rounds 2-5.
// ============================================================================

#define HW   1048576    // 1024*1024
#define BHWu 8388608u   // 8*HW
#define NHu  4194304u   // BHW/2 = packed entries per parity

// ---------------------------------------------------------------------- RNG
__device__ __host__ __forceinline__ void tf2x32(uint32_t k0, uint32_t k1,
                                                uint32_t x0, uint32_t x1,
                                                uint32_t& o0, uint32_t& o1) {
  uint32_t k2 = k0 ^ k1 ^ 0x1BD11BDAu;
  x0 += k0; x1 += k1;
#define RDD(r) { x0 += x1; x1 = (x1 << (r)) | (x1 >> (32 - (r))); x1 ^= x0; }
  RDD(13) RDD(15) RDD(26) RDD(6)
  x0 += k1; x1 += k2 + 1u;
  RDD(17) RDD(29) RDD(16) RDD(24)
  x0 += k2; x1 += k0 + 2u;
  RDD(13) RDD(15) RDD(26) RDD(6)
  x0 += k0; x1 += k1 + 3u;
  RDD(17) RDD(29) RDD(16) RDD(24)
  x0 += k1; x1 += k2 + 4u;
  RDD(13) RDD(15) RDD(26) RDD(6)
  x0 += k2; x1 += k0 + 5u;
#undef RDD
  o0 = x0; o1 = x1;
}

// ------------------------------------------------- XLA-CPU Cephes expf clone
__device__ __forceinline__ float xla_expf(float input) {
  float x  = fmaxf(fminf(input, 88.3762626647950f), -88.3762626647949f);
  float fx = floorf(fmaf(x, 1.44269504088896341f, 0.5f));
  float tmp = __fmul_rn(0.693359375f, fx);
  float z   = __fmul_rn(-2.12194440e-4f, fx);
  x = __fsub_rn(x, tmp);
  x = __fsub_rn(x, z);
  z = __fmul_rn(x, x);
  float y = fmaf(x, 1.9875691500e-4f, 1.3981999507e-3f);
  y = fmaf(y, x, 8.3334519073e-3f);
  y = fmaf(y, x, 4.1665795894e-2f);
  y = fmaf(y, x, 1.6666665459e-1f);
  y = fmaf(y, x, 5.0000001201e-1f);
  y = fmaf(y, z, x);
  y = __fadd_rn(y, 1.0f);
  int n = (int)fx;
  float p2n = __int_as_float((n + 127) << 23);
  return fmaxf(__fmul_rn(y, p2n), input);
}

#define BY(v, i) ((uint32_t)(((v) >> ((i) * 8)) & 0xffu))

// ------------------------------------------------------------------- kernels
// prep_row: one block per (b,y) row. Reads X 8ch (coalesced), writes ch1-7
// pass-through to out, ids u8, and parity-packed dHNN via LDS repack
// (repack mapping verified in round 5's passing coop kernel).
__global__ __launch_bounds__(256) void prep_row(const float* __restrict__ X,
                                                const float* __restrict__ W,
                                                const float* __restrict__ Bb,
                                                float* __restrict__ dHNN,
                                                uint8_t* __restrict__ ids,
                                                float* __restrict__ out) {
  const int tid = (int)threadIdx.x;
  uint32_t row = blockIdx.x;            // 0..8191
  uint32_t b = row >> 10, y = row & 1023u;
  const float4* xb = (const float4*)(X + ((size_t)b << 23));
  float4*       ob = (float4*)(out + ((size_t)b << 23));
  uint32_t fq = (y << 8) + (uint32_t)tid;     // float4 idx within plane
  float4 xc[8];
#pragma unroll
  for (int c = 0; c < 8; c++) xc[c] = xb[((uint32_t)c << 18) + fq];
#pragma unroll
  for (int c = 1; c < 8; c++) ob[((uint32_t)c << 18) + fq] = xc[c];
  uchar4 v;
  v.x = (uint8_t)(int)xc[0].x; v.y = (uint8_t)(int)xc[0].y;
  v.z = (uint8_t)(int)xc[0].z; v.w = (uint8_t)(int)xc[0].w;
  *(uchar4*)(ids + (b << 20) + (y << 10) + 4u * (uint32_t)tid) = v;

  __shared__ float4 pack[2][512];       // 16 KiB, one row parity-packed
#pragma unroll
  for (int j = 0; j < 4; j++) {         // pixel xj = 4*tid + j
    float4 r;
#pragma unroll
    for (int o = 0; o < 4; o++) {
      float acc = 0.0f;
#pragma unroll
      for (int c = 0; c < 8; c++)
        acc = __fadd_rn(acc, __fmul_rn(((const float*)&xc[c])[j], W[o * 8 + c]));
      ((float*)&r)[o] = __fadd_rn(acc, Bb[o]);
    }
    pack[(y + (uint32_t)j) & 1u][(tid << 1) | (j >> 1)] = r;   // slot = xj>>1
  }
  __syncthreads();
  uint32_t qb = (b << 19) | (y << 9);
  float4* d4 = (float4*)dHNN;
  d4[qb + (uint32_t)tid]              = pack[0][tid];
  d4[qb + (uint32_t)tid + 256u]       = pack[0][tid + 256];
  d4[NHu + qb + (uint32_t)tid]        = pack[1][tid];
  d4[NHu + qb + (uint32_t)tid + 256u] = pack[1][tid + 256];
}

// half_step4: 4 active pixels per thread (same row, x = X8+2k+c, k=0..3).
// In-place race-free: all bytes USED from neighbor loads are passive parity
// (never written this step); our own active bytes are written only by us.
// LAST=1 (step 7): write out-ch0 for the full 8-px span instead of ids.
template <int LAST>
__global__ __launch_bounds__(256) void half_step4(uint8_t* __restrict__ ids,
                                                  const float* __restrict__ dHNN,
                                                  float* __restrict__ out,
                                                  uint32_t dk0, uint32_t dk1,
                                                  uint32_t uk0, uint32_t uk1,
                                                  int subi) {
  uint32_t n   = blockIdx.x * 256u + (uint32_t)threadIdx.x;  // 0 .. 2^20-1
  uint32_t sub = (uint32_t)subi;
  uint32_t b   = n >> 17;
  uint32_t y   = (n >> 7) & 1023u;
  uint32_t c   = (y + sub) & 1u;
  uint32_t X8  = (n & 127u) << 3;       // byte col base; x_k = X8 + 2k + c
  uint32_t rowp = (b << 20) | (y << 10);
  uint32_t upp  = (b << 20) | (((y + 1u) & 1023u) << 10);
  uint32_t dnp  = (b << 20) | (((y - 1u) & 1023u) << 10);

  const float4* d4 = (const float4*)dHNN + (size_t)sub * NHu + ((size_t)n << 2);
  float4 dnn0 = d4[0], dnn1 = d4[1], dnn2 = d4[2], dnn3 = d4[3];

  uint64_t mid = *(const uint64_t*)(ids + rowp + X8);
  uint64_t up  = *(const uint64_t*)(ids + upp + X8);
  uint64_t dn  = *(const uint64_t*)(ids + dnp + X8);
  uint32_t e   = c ? (uint32_t)ids[rowp + ((X8 + 8u) & 1023u)]
                   : (uint32_t)ids[rowp + ((X8 + 1023u) & 1023u)];

  uint32_t nw[4];
#pragma unroll
  for (int k = 0; k < 4; k++) {
    uint32_t x = X8 + 2u * (uint32_t)k + c;
    uint32_t p = rowp + x;
    uint32_t self  = BY(mid, 2 * k) , dummy = 0; (void)dummy;
    self = c ? BY(mid, 2 * k + 1) : BY(mid, 2 * k);
    uint32_t left  = c ? BY(mid, 2 * k)
                       : ((k == 0) ? e : BY(mid, 2 * k - 1));
    uint32_t right = c ? ((k == 3) ? e : BY(mid, 2 * k + 2))
                       : BY(mid, 2 * k + 1);
    uint32_t n0 = c ? BY(up, 2 * k + 1) : BY(up, 2 * k);   // roll(-1,0): y+1
    uint32_t n1 = c ? BY(dn, 2 * k + 1) : BY(dn, 2 * k);   // roll(+1,0): y-1

    uint32_t d0, d1, u0, u1;
    tf2x32(dk0, dk1, 0u, p, d0, d1);            // randint lower_bits
    uint32_t db = d0 ^ d1;
    tf2x32(uk0, uk1, 0u, p, u0, u1);            // uniform bits
    uint32_t ub = u0 ^ u1;
    int   dir = (int)(db & 3u);
    float u   = __fsub_rn(__uint_as_float((ub >> 9) | 0x3F800000u), 1.0f);

    uint32_t s  = (dir == 0) ? n0 : (dir == 1) ? n1 : (dir == 2) ? right : left;
    float4 dnnk = (k == 0) ? dnn0 : (k == 1) ? dnn1 : (k == 2) ? dnn2 : dnn3;
    float dH_nn = (dir == 0) ? dnnk.x : (dir == 1) ? dnnk.y
                : (dir == 2) ? dnnk.z : dnnk.w;
    int dadh = ((int)(n0 != s) + (int)(n1 != s) + (int)(right != s) + (int)(left != s))
             - ((int)(n0 != self) + (int)(n1 != self) + (int)(right != self) + (int)(left != self));
    float dH = __fadd_rn((float)dadh, dH_nn);
    bool acc = (u < xla_expf(-dH));
    if (!LAST) { if (acc) ids[p] = (uint8_t)s; }
    nw[k] = acc ? s : self;
  }

  if (LAST) {
    // out ch0 for px X8..X8+7: active bytes (parity c) from nw, passive from mid.
    float f[8];
#pragma unroll
    for (int j = 0; j < 8; j++) {
      uint32_t bj = (((uint32_t)j & 1u) == c) ? nw[j >> 1] : BY(mid, j);
      f[j] = (float)bj;
    }
    float4 f0 = {f[0], f[1], f[2], f[3]};
    float4 f1 = {f[4], f[5], f[6], f[7]};
    float* op = out + ((size_t)b << 23) + (y << 10) + X8;
    *(float4*)op       = f0;
    *(float4*)(op + 4) = f1;
  }
}

// ----------------------------------------------- fallback (small-ws) kernels
__device__ __forceinline__ void metro_one(uint32_t u, uint32_t sub,
                                          uint8_t* __restrict__ ids,
                                          const float* __restrict__ dHNN,
                                          uint32_t dk0, uint32_t dk1,
                                          uint32_t uk0, uint32_t uk1) {
  uint32_t b = u >> 19;
  uint32_t r = u & 524287u;
  uint32_t y = r >> 9;
  uint32_t i = r & 511u;
  uint32_t x = (i << 1) | ((y + sub) & 1u);
  uint32_t p = (b << 20) | (y << 10) | x;
  float4 dnn = ((const float4*)dHNN)[sub * NHu + u];
  uint32_t d0, d1, u0, u1;
  tf2x32(dk0, dk1, 0u, p, d0, d1);
  uint32_t db = d0 ^ d1;
  tf2x32(uk0, uk1, 0u, p, u0, u1);
  uint32_t ub = u0 ^ u1;
  int   dir = (int)(db & 3u);
  float uu  = __fsub_rn(__uint_as_float((ub >> 9) | 0x3F800000u), 1.0f);
  uint32_t yN = (y + 1) & 1023u, yP = (y - 1) & 1023u;
  uint32_t xN = (x + 1) & 1023u, xP = (x - 1) & 1023u;
  uint32_t base = b << 20;
  uint32_t cc = ids[p];
  uint32_t n0 = ids[base + (yN << 10) + x];
  uint32_t n1 = ids[base + (yP << 10) + x];
  uint32_t n2 = ids[base + (y << 10) + xN];
  uint32_t n3 = ids[base + (y << 10) + xP];
  uint32_t s  = (dir == 0) ? n0 : (dir == 1) ? n1 : (dir == 2) ? n2 : n3;
  float dH_nn = (dir == 0) ? dnn.x : (dir == 1) ? dnn.y : (dir == 2) ? dnn.z : dnn.w;
  int dadh = ((int)(n0 != s) + (int)(n1 != s) + (int)(n2 != s) + (int)(n3 != s))
           - ((int)(n0 != cc) + (int)(n1 != cc) + (int)(n2 != cc) + (int)(n3 != cc));
  float dH = __fadd_rn((float)dadh, dH_nn);
  if (uu < xla_expf(-dH)) ids[p] = (uint8_t)s;
}

__global__ __launch_bounds__(256) void prep4_fb(const float* __restrict__ X,
                                                const float* __restrict__ W,
                                                const float* __restrict__ Bb,
                                                float* __restrict__ dHNN,
                                                uint8_t* __restrict__ ids) {
  int tid = blockIdx.x * 256 + threadIdx.x;
  int e   = tid << 2;
  int b   = e >> 20;
  int yx  = e & (HW - 1);
  int y   = yx >> 10;
  int x0  = yx & 1023;
  int q4  = yx >> 2;
  const float4* xb = (const float4*)(X + ((size_t)b << 23));
  float4 xc[8];
#pragma unroll
  for (int c = 0; c < 8; c++) xc[c] = xb[(c << 18) + q4];
#pragma unroll
  for (int j = 0; j < 4; j++) {
    float4 r;
#pragma unroll
    for (int o = 0; o < 4; o++) {
      float acc = 0.0f;
#pragma unroll
      for (int c = 0; c < 8; c++)
        acc = __fadd_rn(acc, __fmul_rn(((const float*)&xc[c])[j], W[o * 8 + c]));
      ((float*)&r)[o] = __fadd_rn(acc, Bb[o]);
    }
    int xj = x0 + j;
    ((float4*)dHNN)[((xj + y) & 1) * NHu + (uint32_t)((b << 19) | (y << 9) | (xj >> 1))] = r;
  }
  uchar4 v;
  v.x = (uint8_t)(int)xc[0].x; v.y = (uint8_t)(int)xc[0].y;
  v.z = (uint8_t)(int)xc[0].z; v.w = (uint8_t)(int)xc[0].w;
  *(uchar4*)(ids + e) = v;
}

__global__ __launch_bounds__(256) void half_step_fb(uint8_t* __restrict__ ids,
                                                    const float* __restrict__ dHNN,
                                                    uint32_t dk0, uint32_t dk1,
                                                    uint32_t uk0, uint32_t uk1,
                                                    int sub) {
  uint32_t u = blockIdx.x * 256u + threadIdx.x;
  metro_one(u, (uint32_t)sub, ids, dHNN, dk0, dk1, uk0, uk1);
}

__global__ __launch_bounds__(256) void finalize_full_fb(const float* __restrict__ X,
                                                        const uint8_t* __restrict__ ids,
                                                        float* __restrict__ out) {
  int t = blockIdx.x * 256 + threadIdx.x;
  int e = t << 2;
  int c = (e >> 20) & 7;
  float4 r;
  if (c == 0) {
    int b  = e >> 23;
    int yx = e & (HW - 1);
    uchar4 v = *(const uchar4*)(ids + ((size_t)b << 20) + yx);
    r.x = (float)v.x; r.y = (float)v.y; r.z = (float)v.z; r.w = (float)v.w;
  } else {
    r = ((const float4*)X)[t];
  }
  ((float4*)out)[t] = r;
}

// --------------------------------------------------------------------- host
extern "C" void kernel_launch(void* const* d_in, const int* in_sizes, int n_in,
                              void* d_out, int out_size, void* d_ws, size_t ws_size,
                              hipStream_t stream) {
  const float* X  = (const float*)d_in[0];
  const float* W  = (const float*)d_in[1];
  const float* Bb = (const float*)d_in[2];
  float* out = (float*)d_out;

  const size_t DHNN_BYTES = (size_t)BHWu * 16u;       // 134 MB
  const size_t IDS_BYTES  = (size_t)BHWu;             // 8.4 MB

  // Threefry key chain (partitionable stream; verified rounds 2-5).
  uint32_t bk0 = 0u, bk1 = 42u;
  uint32_t keys[8][2];
  for (uint32_t t = 0; t < 8; t++)
    tf2x32(bk0, bk1, 0u, t, keys[t][0], keys[t][1]);
  uint32_t K[8][4];
  for (int t = 0; t < 8; t++) {
    uint32_t k1a, k1b;
    tf2x32(keys[t][0], keys[t][1], 0u, 0u, k1a, k1b);       // k1 (randint arg)
    tf2x32(keys[t][0], keys[t][1], 0u, 1u, K[t][2], K[t][3]); // k2 -> ukey
    tf2x32(k1a, k1b, 0u, 1u, K[t][0], K[t][1]);             // randint kk2 -> dkey
  }

  bool ws_ok = ws_size >= DHNN_BYTES + IDS_BYTES;
  if (ws_ok) {
    float*   dHNN = (float*)d_ws;
    uint8_t* ids  = (uint8_t*)d_ws + DHNN_BYTES;
    prep_row<<<8192, 256, 0, stream>>>(X, W, Bb, dHNN, ids, out);
    for (int t = 0; t < 7; t++)
      half_step4<0><<<4096, 256, 0, stream>>>(ids, dHNN, out,
          K[t][0], K[t][1], K[t][2], K[t][3], t & 1);
    half_step4<1><<<4096, 256, 0, stream>>>(ids, dHNN, out,
        K[7][0], K[7][1], K[7][2], K[7][3], 1);
  } else {
    float*   dHNN = out;                 // dHNN lives in out; ids in ws
    uint8_t* ids  = (uint8_t*)d_ws;
    prep4_fb<<<8192, 256, 0, stream>>>(X, W, Bb, dHNN, ids);
    for (int t = 0; t < 8; t++)
      half_step_fb<<<16384, 256, 0, stream>>>(ids, dHNN,
          K[t][0], K[t][1], K[t][2], K[t][3], t & 1);
    finalize_full_fb<<<65536, 256, 0, stream>>>(X, ids, out);
  }
  (void)in_sizes; (void)n_in; (void)out_size;
}

// Round 7
// 308.353 us; speedup vs baseline: 6.6620x; 1.0191x over previous
//
#include <hip/hip_runtime.h>
#include <stdint.h>

// ============================================================================
// CPM layer, bit-exact JAX reproduction. B=8, C=8, H=W=1024.
// Round 7: dirs consumed in prep (threefry is ids-independent) -> steps read a
// pre-selected dH_nn scalar (4 B/px) + 2-bit dir code instead of the 16 B
// dH_NN vector. Pass-through copy split into a dedicated pure-copy kernel.
// RNG / dot order / Cephes exp bit-identical to passing rounds 2-6.
// ============================================================================

#define HW   1048576    // 1024*1024
#define BHWu 8388608u   // 8*HW
#define NHu  4194304u   // BHW/2 = packed entries per parity

struct KeysDK { uint32_t v[8][2]; };   // per-step randint-internal dkey

// ---------------------------------------------------------------------- RNG
__device__ __host__ __forceinline__ void tf2x32(uint32_t k0, uint32_t k1,
                                                uint32_t x0, uint32_t x1,
                                                uint32_t& o0, uint32_t& o1) {
  uint32_t k2 = k0 ^ k1 ^ 0x1BD11BDAu;
  x0 += k0; x1 += k1;
#define RDD(r) { x0 += x1; x1 = (x1 << (r)) | (x1 >> (32 - (r))); x1 ^= x0; }
  RDD(13) RDD(15) RDD(26) RDD(6)
  x0 += k1; x1 += k2 + 1u;
  RDD(17) RDD(29) RDD(16) RDD(24)
  x0 += k2; x1 += k0 + 2u;
  RDD(13) RDD(15) RDD(26) RDD(6)
  x0 += k0; x1 += k1 + 3u;
  RDD(17) RDD(29) RDD(16) RDD(24)
  x0 += k1; x1 += k2 + 4u;
  RDD(13) RDD(15) RDD(26) RDD(6)
  x0 += k2; x1 += k0 + 5u;
#undef RDD
  o0 = x0; o1 = x1;
}

// ------------------------------------------------- XLA-CPU Cephes expf clone
__device__ __forceinline__ float xla_expf(float input) {
  float x  = fmaxf(fminf(input, 88.3762626647950f), -88.3762626647949f);
  float fx = floorf(fmaf(x, 1.44269504088896341f, 0.5f));
  float tmp = __fmul_rn(0.693359375f, fx);
  float z   = __fmul_rn(-2.12194440e-4f, fx);
  x = __fsub_rn(x, tmp);
  x = __fsub_rn(x, z);
  z = __fmul_rn(x, x);
  float y = fmaf(x, 1.9875691500e-4f, 1.3981999507e-3f);
  y = fmaf(y, x, 8.3334519073e-3f);
  y = fmaf(y, x, 4.1665795894e-2f);
  y = fmaf(y, x, 1.6666665459e-1f);
  y = fmaf(y, x, 5.0000001201e-1f);
  y = fmaf(y, z, x);
  y = __fadd_rn(y, 1.0f);
  int n = (int)fx;
  float p2n = __int_as_float((n + 127) << 23);
  return fmaxf(__fmul_rn(y, p2n), input);
}

#define BY(v, i) ((uint32_t)(((v) >> ((i) * 8)) & 0xffu))

// ------------------------------------------------------------------- kernels
// copy_ch17: out ch1-7 <- X ch1-7. Per b, channels 1..7 are one contiguous
// 28 MB span. grid (7168, 8).
__global__ __launch_bounds__(256) void copy_ch17(const float4* __restrict__ X4,
                                                 float4* __restrict__ O4) {
  size_t base = ((size_t)blockIdx.y << 21) + (1u << 18);   // b*2^21 + ch1
  uint32_t i  = blockIdx.x * 256u + threadIdx.x;           // 0..1,835,007
  O4[base + i] = X4[base + i];
}

// prep_compute: 2 rows/block (grid 4096). Each lane (tid&127) owns 8 px of
// row y+(tid>>7). Computes dH_NN in regs (Eigen no-FMA c-ascending chain,
// bias after), the 4 active-step dirs per px (threefry, ids-independent),
// stores the SELECTED scalar sel[t][u] (float4/plane) + 2-bit dirs (byte) +
// ids (8 B). No dH_NN vector is ever materialized.
__global__ __launch_bounds__(256) void prep_compute(const float* __restrict__ X,
                                                    const float* __restrict__ W,
                                                    const float* __restrict__ Bb,
                                                    float* __restrict__ sel,
                                                    uint8_t* __restrict__ dirp,
                                                    uint8_t* __restrict__ ids,
                                                    KeysDK K) {
  const uint32_t tid   = threadIdx.x;
  const uint32_t lane  = tid & 127u;
  const uint32_t rhalf = tid >> 7;
  const uint32_t row   = blockIdx.x * 2u + rhalf;   // 0..8191
  const uint32_t b = row >> 10, y = row & 1023u;
  const uint32_t ylsb = y & 1u;

  const float4* xb = (const float4*)(X + ((size_t)b << 23));
  const uint32_t fq = (y << 8) + 2u * lane;

  float acc[8][4];
  float x0[8];
#pragma unroll
  for (int c = 0; c < 8; c++) {
    float4 a  = xb[((uint32_t)c << 18) + fq];
    float4 bv = xb[((uint32_t)c << 18) + fq + 1u];
    float xs[8] = {a.x, a.y, a.z, a.w, bv.x, bv.y, bv.z, bv.w};
    if (c == 0) {
#pragma unroll
      for (int px = 0; px < 8; px++) x0[px] = xs[px];
    }
#pragma unroll
    for (int px = 0; px < 8; px++)
#pragma unroll
      for (int o = 0; o < 4; o++) {
        float m = __fmul_rn(xs[px], W[o * 8 + c]);
        acc[px][o] = (c == 0) ? __fadd_rn(0.0f, m) : __fadd_rn(acc[px][o], m);
      }
  }
#pragma unroll
  for (int px = 0; px < 8; px++)
#pragma unroll
    for (int o = 0; o < 4; o++) acc[px][o] = __fadd_rn(acc[px][o], Bb[o]);

  // ids: 8 bytes packed
  {
    uint32_t lo = ((uint32_t)(uint8_t)(int)x0[0])
                | ((uint32_t)(uint8_t)(int)x0[1] << 8)
                | ((uint32_t)(uint8_t)(int)x0[2] << 16)
                | ((uint32_t)(uint8_t)(int)x0[3] << 24);
    uint32_t hi = ((uint32_t)(uint8_t)(int)x0[4])
                | ((uint32_t)(uint8_t)(int)x0[5] << 8)
                | ((uint32_t)(uint8_t)(int)x0[6] << 16)
                | ((uint32_t)(uint8_t)(int)x0[7] << 24);
    uint2 v = {lo, hi};
    *(uint2*)(ids + (b << 20) + (y << 10) + 8u * lane) = v;
  }

  // dirs + selected scalar, per step-quadrant js and x-parity pb
  const uint32_t rowbase = (b << 19) + (y << 9);
  const uint32_t pbase   = (b << 20) | (y << 10);
  for (int js = 0; js < 4; js++) {
#pragma unroll
    for (int pb = 0; pb < 2; pb++) {
      uint32_t s0 = ylsb ^ (uint32_t)pb;          // t = 2*js + s0
      uint32_t ka0 = s0 ? K.v[1][0] : K.v[0][0], kb0 = s0 ? K.v[1][1] : K.v[0][1];
      uint32_t ka1 = s0 ? K.v[3][0] : K.v[2][0], kb1 = s0 ? K.v[3][1] : K.v[2][1];
      uint32_t ka2 = s0 ? K.v[5][0] : K.v[4][0], kb2 = s0 ? K.v[5][1] : K.v[4][1];
      uint32_t ka3 = s0 ? K.v[7][0] : K.v[6][0], kb3 = s0 ? K.v[7][1] : K.v[6][1];
      uint32_t ka = (js == 0) ? ka0 : (js == 1) ? ka1 : (js == 2) ? ka2 : ka3;
      uint32_t kb = (js == 0) ? kb0 : (js == 1) ? kb1 : (js == 2) ? kb2 : kb3;
      float4 sv; uint32_t dby = 0;
#pragma unroll
      for (int k = 0; k < 4; k++) {
        int px = 2 * k + pb;
        uint32_t x = 8u * lane + (uint32_t)px;
        uint32_t p = pbase | x;
        uint32_t o0, o1;
        tf2x32(ka, kb, 0u, p, o0, o1);
        uint32_t dir = (o0 ^ o1) & 3u;
        dby |= dir << (2 * k);
        float v = (dir == 0) ? acc[px][0] : (dir == 1) ? acc[px][1]
                : (dir == 2) ? acc[px][2] : acc[px][3];
        ((float*)&sv)[k] = v;
      }
      uint32_t t = 2u * (uint32_t)js + s0;
      ((float4*)(sel + (size_t)t * NHu + rowbase))[lane] = sv;
      dirp[((size_t)t << 20) + (b << 17) + (y << 7) + lane] = (uint8_t)dby;
    }
  }
}

// half_step4: 4 active px/thread. Reads sel float4 + dir byte (no dH_NN
// vector). In-place race-free by checkerboard parity. LAST=1: write out-ch0.
template <int LAST>
__global__ __launch_bounds__(256) void half_step4(uint8_t* __restrict__ ids,
                                                  const float* __restrict__ sel,
                                                  const uint8_t* __restrict__ dirp,
                                                  float* __restrict__ out,
                                                  uint32_t uk0, uint32_t uk1,
                                                  int stepi, int subi) {
  uint32_t n   = blockIdx.x * 256u + (uint32_t)threadIdx.x;  // 0 .. 2^20-1
  uint32_t sub = (uint32_t)subi;
  uint32_t b   = n >> 17;
  uint32_t y   = (n >> 7) & 1023u;
  uint32_t c   = (y + sub) & 1u;
  uint32_t X8  = (n & 127u) << 3;       // byte col base; x_k = X8 + 2k + c
  uint32_t rowp = (b << 20) | (y << 10);
  uint32_t upp  = (b << 20) | (((y + 1u) & 1023u) << 10);
  uint32_t dnp  = (b << 20) | (((y - 1u) & 1023u) << 10);

  float4   sv  = ((const float4*)(sel + (size_t)stepi * NHu))[n];
  uint32_t dby = dirp[((size_t)stepi << 20) + n];

  uint64_t mid = *(const uint64_t*)(ids + rowp + X8);
  uint64_t up  = *(const uint64_t*)(ids + upp + X8);
  uint64_t dn  = *(const uint64_t*)(ids + dnp + X8);
  uint32_t e   = c ? (uint32_t)ids[rowp + ((X8 + 8u) & 1023u)]
                   : (uint32_t)ids[rowp + ((X8 + 1023u) & 1023u)];

  uint32_t nw[4];
#pragma unroll
  for (int k = 0; k < 4; k++) {
    uint32_t x = X8 + 2u * (uint32_t)k + c;
    uint32_t p = rowp + x;
    uint32_t self  = c ? BY(mid, 2 * k + 1) : BY(mid, 2 * k);
    uint32_t left  = c ? BY(mid, 2 * k)
                       : ((k == 0) ? e : BY(mid, 2 * k - 1));
    uint32_t right = c ? ((k == 3) ? e : BY(mid, 2 * k + 2))
                       : BY(mid, 2 * k + 1);
    uint32_t n0 = c ? BY(up, 2 * k + 1) : BY(up, 2 * k);   // roll(-1,0): y+1
    uint32_t n1 = c ? BY(dn, 2 * k + 1) : BY(dn, 2 * k);   // roll(+1,0): y-1

    uint32_t u0, u1;
    tf2x32(uk0, uk1, 0u, p, u0, u1);            // uniform bits
    uint32_t ub = u0 ^ u1;
    float u = __fsub_rn(__uint_as_float((ub >> 9) | 0x3F800000u), 1.0f);

    int dir = (int)((dby >> (2 * k)) & 3u);
    uint32_t s  = (dir == 0) ? n0 : (dir == 1) ? n1 : (dir == 2) ? right : left;
    float dH_nn = ((const float*)&sv)[k];
    int dadh = ((int)(n0 != s) + (int)(n1 != s) + (int)(right != s) + (int)(left != s))
             - ((int)(n0 != self) + (int)(n1 != self) + (int)(right != self) + (int)(left != self));
    float dH = __fadd_rn((float)dadh, dH_nn);
    bool acc = (u < xla_expf(-dH));
    if (!LAST) { if (acc) ids[p] = (uint8_t)s; }
    nw[k] = acc ? s : self;
  }

  if (LAST) {
    float f[8];
#pragma unroll
    for (int j = 0; j < 8; j++) {
      uint32_t bj = (((uint32_t)j & 1u) == c) ? nw[j >> 1] : BY(mid, j);
      f[j] = (float)bj;
    }
    float4 f0 = {f[0], f[1], f[2], f[3]};
    float4 f1 = {f[4], f[5], f[6], f[7]};
    float* op = out + ((size_t)b << 23) + (y << 10) + X8;
    *(float4*)op       = f0;
    *(float4*)(op + 4) = f1;
  }
}

// ----------------------------------------------- fallback (small-ws) kernels
__device__ __forceinline__ void metro_one(uint32_t u, uint32_t sub,
                                          uint8_t* __restrict__ ids,
                                          const float* __restrict__ dHNN,
                                          uint32_t dk0, uint32_t dk1,
                                          uint32_t uk0, uint32_t uk1) {
  uint32_t b = u >> 19;
  uint32_t r = u & 524287u;
  uint32_t y = r >> 9;
  uint32_t i = r & 511u;
  uint32_t x = (i << 1) | ((y + sub) & 1u);
  uint32_t p = (b << 20) | (y << 10) | x;
  float4 dnn = ((const float4*)dHNN)[sub * NHu + u];
  uint32_t d0, d1, u0, u1;
  tf2x32(dk0, dk1, 0u, p, d0, d1);
  uint32_t db = d0 ^ d1;
  tf2x32(uk0, uk1, 0u, p, u0, u1);
  uint32_t ub = u0 ^ u1;
  int   dir = (int)(db & 3u);
  float uu  = __fsub_rn(__uint_as_float((ub >> 9) | 0x3F800000u), 1.0f);
  uint32_t yN = (y + 1) & 1023u, yP = (y - 1) & 1023u;
  uint32_t xN = (x + 1) & 1023u, xP = (x - 1) & 1023u;
  uint32_t base = b << 20;
  uint32_t cc = ids[p];
  uint32_t n0 = ids[base + (yN << 10) + x];
  uint32_t n1 = ids[base + (yP << 10) + x];
  uint32_t n2 = ids[base + (y << 10) + xN];
  uint32_t n3 = ids[base + (y << 10) + xP];
  uint32_t s  = (dir == 0) ? n0 : (dir == 1) ? n1 : (dir == 2) ? n2 : n3;
  float dH_nn = (dir == 0) ? dnn.x : (dir == 1) ? dnn.y : (dir == 2) ? dnn.z : dnn.w;
  int dadh = ((int)(n0 != s) + (int)(n1 != s) + (int)(n2 != s) + (int)(n3 != s))
           - ((int)(n0 != cc) + (int)(n1 != cc) + (int)(n2 != cc) + (int)(n3 != cc));
  float dH = __fadd_rn((float)dadh, dH_nn);
  if (uu < xla_expf(-dH)) ids[p] = (uint8_t)s;
}

__global__ __launch_bounds__(256) void prep4_fb(const float* __restrict__ X,
                                                const float* __restrict__ W,
                                                const float* __restrict__ Bb,
                                                float* __restrict__ dHNN,
                                                uint8_t* __restrict__ ids) {
  int tid = blockIdx.x * 256 + threadIdx.x;
  int e   = tid << 2;
  int b   = e >> 20;
  int yx  = e & (HW - 1);
  int y   = yx >> 10;
  int x0  = yx & 1023;
  int q4  = yx >> 2;
  const float4* xb = (const float4*)(X + ((size_t)b << 23));
  float4 xc[8];
#pragma unroll
  for (int c = 0; c < 8; c++) xc[c] = xb[(c << 18) + q4];
#pragma unroll
  for (int j = 0; j < 4; j++) {
    float4 r;
#pragma unroll
    for (int o = 0; o < 4; o++) {
      float acc = 0.0f;
#pragma unroll
      for (int c = 0; c < 8; c++)
        acc = __fadd_rn(acc, __fmul_rn(((const float*)&xc[c])[j], W[o * 8 + c]));
      ((float*)&r)[o] = __fadd_rn(acc, Bb[o]);
    }
    int xj = x0 + j;
    ((float4*)dHNN)[((xj + y) & 1) * NHu + (uint32_t)((b << 19) | (y << 9) | (xj >> 1))] = r;
  }
  uchar4 v;
  v.x = (uint8_t)(int)xc[0].x; v.y = (uint8_t)(int)xc[0].y;
  v.z = (uint8_t)(int)xc[0].z; v.w = (uint8_t)(int)xc[0].w;
  *(uchar4*)(ids + e) = v;
}

__global__ __launch_bounds__(256) void half_step_fb(uint8_t* __restrict__ ids,
                                                    const float* __restrict__ dHNN,
                                                    uint32_t dk0, uint32_t dk1,
                                                    uint32_t uk0, uint32_t uk1,
                                                    int sub) {
  uint32_t u = blockIdx.x * 256u + threadIdx.x;
  metro_one(u, (uint32_t)sub, ids, dHNN, dk0, dk1, uk0, uk1);
}

__global__ __launch_bounds__(256) void finalize_full_fb(const float* __restrict__ X,
                                                        const uint8_t* __restrict__ ids,
                                                        float* __restrict__ out) {
  int t = blockIdx.x * 256 + threadIdx.x;
  int e = t << 2;
  int c = (e >> 20) & 7;
  float4 r;
  if (c == 0) {
    int b  = e >> 23;
    int yx = e & (HW - 1);
    uchar4 v = *(const uchar4*)(ids + ((size_t)b << 20) + yx);
    r.x = (float)v.x; r.y = (float)v.y; r.z = (float)v.z; r.w = (float)v.w;
  } else {
    r = ((const float4*)X)[t];
  }
  ((float4*)out)[t] = r;
}

// --------------------------------------------------------------------- host
extern "C" void kernel_launch(void* const* d_in, const int* in_sizes, int n_in,
                              void* d_out, int out_size, void* d_ws, size_t ws_size,
                              hipStream_t stream) {
  const float* X  = (const float*)d_in[0];
  const float* W  = (const float*)d_in[1];
  const float* Bb = (const float*)d_in[2];
  float* out = (float*)d_out;

  const size_t SEL_BYTES = (size_t)NHu * 8u * 4u;     // 134.2 MB
  const size_t DIR_BYTES = (size_t)NHu * 2u;          // 8.4 MB
  const size_t IDS_BYTES = (size_t)BHWu;              // 8.4 MB

  // Threefry key chain (partitionable stream; verified rounds 2-6).
  uint32_t bk0 = 0u, bk1 = 42u;
  uint32_t keys[8][2];
  for (uint32_t t = 0; t < 8; t++)
    tf2x32(bk0, bk1, 0u, t, keys[t][0], keys[t][1]);
  uint32_t K[8][4];
  KeysDK DK;
  for (int t = 0; t < 8; t++) {
    uint32_t k1a, k1b;
    tf2x32(keys[t][0], keys[t][1], 0u, 0u, k1a, k1b);         // k1 (randint arg)
    tf2x32(keys[t][0], keys[t][1], 0u, 1u, K[t][2], K[t][3]); // k2 -> ukey
    tf2x32(k1a, k1b, 0u, 1u, K[t][0], K[t][1]);               // randint kk2 -> dkey
    DK.v[t][0] = K[t][0]; DK.v[t][1] = K[t][1];
  }

  bool ws_ok = ws_size >= SEL_BYTES + DIR_BYTES + IDS_BYTES;
  if (ws_ok) {
    float*   sel  = (float*)d_ws;
    uint8_t* dirp = (uint8_t*)d_ws + SEL_BYTES;
    uint8_t* ids  = (uint8_t*)d_ws + SEL_BYTES + DIR_BYTES;

    prep_compute<<<4096, 256, 0, stream>>>(X, W, Bb, sel, dirp, ids, DK);
    copy_ch17<<<dim3(7168, 8), 256, 0, stream>>>((const float4*)X, (float4*)out);
    for (int t = 0; t < 7; t++)
      half_step4<0><<<4096, 256, 0, stream>>>(ids, sel, dirp, out,
          K[t][2], K[t][3], t, t & 1);
    half_step4<1><<<4096, 256, 0, stream>>>(ids, sel, dirp, out,
        K[7][2], K[7][3], 7, 1);
  } else {
    float*   dHNN = out;                 // dHNN lives in out; ids in ws
    uint8_t* ids  = (uint8_t*)d_ws;
    prep4_fb<<<8192, 256, 0, stream>>>(X, W, Bb, dHNN, ids);
    for (int t = 0; t < 8; t++)
      half_step_fb<<<16384, 256, 0, stream>>>(ids, dHNN,
          K[t][0], K[t][1], K[t][2], K[t][3], t & 1);
    finalize_full_fb<<<65536, 256, 0, stream>>>(X, ids, out);
  }
  (void)in_sizes; (void)n_in; (void)out_size;
}

// Round 8
// 292.117 us; speedup vs baseline: 7.0322x; 1.0556x over previous
//
#include <hip/hip_runtime.h>
#include <stdint.h>

// ============================================================================
// CPM layer, bit-exact JAX reproduction. B=8, C=8, H=W=1024.
// Round 8: prep precomputes a 1-byte DECISION CODE per px-step:
//   low nibble = d*+5 where d* = max{d in [-4,4]: u < exp(-(d+v))} (-5 if none)
//   bits 4-5   = dir
// found by 4-eval binary search over the bit-exact accept predicate
// (monotone in integer d: consecutive exp values differ by x e >> approx err).
// Steps become pure byte logic: accept <=> dadh+5 <= nibble. The ch1-7
// pass-through copy is fused into the now VALU-bound prep (8:7 block split).
// RNG / dot order / Cephes exp bit-identical to passing rounds 2-7.
// ============================================================================

#define HW    1048576    // 1024*1024
#define BHWu  8388608u   // 8*HW
#define NHu   4194304u   // BHW/2 = packed entries per parity (code plane bytes)
#define CPYF4 14680064u  // ch1-7 float4 count = 8*7*262144
#define CPYB  3584       // copy blocks (x 256 thr x 16 f4 = CPYF4)

struct KeysK { uint32_t d[8][2]; uint32_t u[8][2]; };

// ---------------------------------------------------------------------- RNG
__device__ __host__ __forceinline__ void tf2x32(uint32_t k0, uint32_t k1,
                                                uint32_t x0, uint32_t x1,
                                                uint32_t& o0, uint32_t& o1) {
  uint32_t k2 = k0 ^ k1 ^ 0x1BD11BDAu;
  x0 += k0; x1 += k1;
#define RDD(r) { x0 += x1; x1 = (x1 << (r)) | (x1 >> (32 - (r))); x1 ^= x0; }
  RDD(13) RDD(15) RDD(26) RDD(6)
  x0 += k1; x1 += k2 + 1u;
  RDD(17) RDD(29) RDD(16) RDD(24)
  x0 += k2; x1 += k0 + 2u;
  RDD(13) RDD(15) RDD(26) RDD(6)
  x0 += k0; x1 += k1 + 3u;
  RDD(17) RDD(29) RDD(16) RDD(24)
  x0 += k1; x1 += k2 + 4u;
  RDD(13) RDD(15) RDD(26) RDD(6)
  x0 += k2; x1 += k0 + 5u;
#undef RDD
  o0 = x0; o1 = x1;
}

// ------------------------------------------------- XLA-CPU Cephes expf clone
__device__ __forceinline__ float xla_expf(float input) {
  float x  = fmaxf(fminf(input, 88.3762626647950f), -88.3762626647949f);
  float fx = floorf(fmaf(x, 1.44269504088896341f, 0.5f));
  float tmp = __fmul_rn(0.693359375f, fx);
  float z   = __fmul_rn(-2.12194440e-4f, fx);
  x = __fsub_rn(x, tmp);
  x = __fsub_rn(x, z);
  z = __fmul_rn(x, x);
  float y = fmaf(x, 1.9875691500e-4f, 1.3981999507e-3f);
  y = fmaf(y, x, 8.3334519073e-3f);
  y = fmaf(y, x, 4.1665795894e-2f);
  y = fmaf(y, x, 1.6666665459e-1f);
  y = fmaf(y, x, 5.0000001201e-1f);
  y = fmaf(y, z, x);
  y = __fadd_rn(y, 1.0f);
  int n = (int)fx;
  float p2n = __int_as_float((n + 127) << 23);
  return fmaxf(__fmul_rn(y, p2n), input);
}

#define BY(v, i) ((uint32_t)(((v) >> ((i) * 8)) & 0xffu))
// bit-exact accept predicate at integer d (same expr as the step's exp(-dH))
#define ACC_D(dd) (u < xla_expf(-__fadd_rn((float)(dd), v)))

// ------------------------------------------------------------------- kernels
// prep_fused: groups of 15 blocks = 8 compute + 7 copy.
//  compute: 2 rows/block; per px computes dH_NN (Eigen no-FMA chain), then per
//   active step: dir cipher, uniform cipher, 4-eval binary search -> code byte.
//  copy: 16 float4/thread of the X ch1-7 -> out pass-through.
__global__ __launch_bounds__(256) void prep_fused(const float* __restrict__ X,
                                                  const float* __restrict__ W,
                                                  const float* __restrict__ Bb,
                                                  uint8_t* __restrict__ code,
                                                  uint8_t* __restrict__ ids,
                                                  float* __restrict__ out,
                                                  KeysK K) {
  const uint32_t tid = threadIdx.x;
  const uint32_t g = blockIdx.x, group = g / 15u, r = g - group * 15u;
  if (r >= 8u) {                              // ---- copy role
    uint32_t j = group * 7u + (r - 8u);       // 0..3583
    const float4* X4 = (const float4*)X;
    float4*       O4 = (float4*)out;
#pragma unroll
    for (uint32_t i = 0; i < 16u; i++) {
      uint32_t F = j * 4096u + i * 256u + tid;       // < CPYF4
      uint32_t b = F / 1835008u;
      uint32_t rem = F - b * 1835008u;
      size_t idx = ((size_t)b << 21) + 262144u + rem;  // b*2^21 + ch1 offset
      O4[idx] = X4[idx];
    }
    return;
  }
  // ---- compute role
  const uint32_t cb    = group * 8u + r;      // 0..4095
  const uint32_t lane  = tid & 127u;
  const uint32_t rhalf = tid >> 7;
  const uint32_t row   = cb * 2u + rhalf;     // 0..8191
  const uint32_t b = row >> 10, y = row & 1023u;
  const uint32_t ylsb = y & 1u;

  const float4* xb = (const float4*)(X + ((size_t)b << 23));
  const uint32_t fq = (y << 8) + 2u * lane;

  float acc[8][4];
  float x0[8];
#pragma unroll
  for (int c = 0; c < 8; c++) {
    float4 a  = xb[((uint32_t)c << 18) + fq];
    float4 bv = xb[((uint32_t)c << 18) + fq + 1u];
    float xs[8] = {a.x, a.y, a.z, a.w, bv.x, bv.y, bv.z, bv.w};
    if (c == 0) {
#pragma unroll
      for (int px = 0; px < 8; px++) x0[px] = xs[px];
    }
#pragma unroll
    for (int px = 0; px < 8; px++)
#pragma unroll
      for (int o = 0; o < 4; o++) {
        float m = __fmul_rn(xs[px], W[o * 8 + c]);
        acc[px][o] = (c == 0) ? __fadd_rn(0.0f, m) : __fadd_rn(acc[px][o], m);
      }
  }
#pragma unroll
  for (int px = 0; px < 8; px++)
#pragma unroll
    for (int o = 0; o < 4; o++) acc[px][o] = __fadd_rn(acc[px][o], Bb[o]);

  {  // ids: 8 bytes packed
    uint32_t lo = ((uint32_t)(uint8_t)(int)x0[0])
                | ((uint32_t)(uint8_t)(int)x0[1] << 8)
                | ((uint32_t)(uint8_t)(int)x0[2] << 16)
                | ((uint32_t)(uint8_t)(int)x0[3] << 24);
    uint32_t hi = ((uint32_t)(uint8_t)(int)x0[4])
                | ((uint32_t)(uint8_t)(int)x0[5] << 8)
                | ((uint32_t)(uint8_t)(int)x0[6] << 16)
                | ((uint32_t)(uint8_t)(int)x0[7] << 24);
    uint2 v2 = {lo, hi};
    *(uint2*)(ids + (b << 20) + (y << 10) + 8u * lane) = v2;
  }

  const uint32_t pbase   = (b << 20) | (y << 10);
  const uint32_t codeoff = (b << 19) | (y << 9) | (4u * lane);
  for (int js = 0; js < 4; js++) {
#pragma unroll
    for (int pb = 0; pb < 2; pb++) {
      uint32_t s0 = ylsb ^ (uint32_t)pb;      // step t = 2*js + s0
      uint32_t dka = (js == 0) ? (s0 ? K.d[1][0] : K.d[0][0])
                   : (js == 1) ? (s0 ? K.d[3][0] : K.d[2][0])
                   : (js == 2) ? (s0 ? K.d[5][0] : K.d[4][0])
                               : (s0 ? K.d[7][0] : K.d[6][0]);
      uint32_t dkb = (js == 0) ? (s0 ? K.d[1][1] : K.d[0][1])
                   : (js == 1) ? (s0 ? K.d[3][1] : K.d[2][1])
                   : (js == 2) ? (s0 ? K.d[5][1] : K.d[4][1])
                               : (s0 ? K.d[7][1] : K.d[6][1]);
      uint32_t uka = (js == 0) ? (s0 ? K.u[1][0] : K.u[0][0])
                   : (js == 1) ? (s0 ? K.u[3][0] : K.u[2][0])
                   : (js == 2) ? (s0 ? K.u[5][0] : K.u[4][0])
                               : (s0 ? K.u[7][0] : K.u[6][0]);
      uint32_t ukb = (js == 0) ? (s0 ? K.u[1][1] : K.u[0][1])
                   : (js == 1) ? (s0 ? K.u[3][1] : K.u[2][1])
                   : (js == 2) ? (s0 ? K.u[5][1] : K.u[4][1])
                               : (s0 ? K.u[7][1] : K.u[6][1]);
      uint32_t cword = 0;
#pragma unroll
      for (int k = 0; k < 4; k++) {
        int px = 2 * k + pb;
        uint32_t p = pbase | (8u * lane + (uint32_t)px);
        uint32_t o0, o1, q0, q1;
        tf2x32(dka, dkb, 0u, p, o0, o1);
        uint32_t dir = (o0 ^ o1) & 3u;
        tf2x32(uka, ukb, 0u, p, q0, q1);
        uint32_t ub = q0 ^ q1;
        float u = __fsub_rn(__uint_as_float((ub >> 9) | 0x3F800000u), 1.0f);
        float v = (dir == 0) ? acc[px][0] : (dir == 1) ? acc[px][1]
                : (dir == 2) ? acc[px][2] : acc[px][3];
        // 4-eval binary search for d* = max accepted d (monotone in d)
        bool a0 = ACC_D(0);
        int  d1 = a0 ? 2 : -2;            bool a1 = ACC_D(d1);
        int  d2 = a0 ? (a1 ? 3 : 1) : (a1 ? -1 : -3);
                                          bool a2 = ACC_D(d2);
        int  d3 = a0 ? 4 : -4;            bool a3 = ACC_D(d3);
        int dstar = a0 ? (a1 ? (a2 ? (a3 ? 4 : 3) : 2) : (a2 ? 1 : 0))
                       : (a1 ? (a2 ? -1 : -2) : (a2 ? -3 : (a3 ? -4 : -5)));
        cword |= (uint32_t)((uint32_t)(dstar + 5) | (dir << 4)) << (8 * k);
      }
      uint32_t t = 2u * (uint32_t)js + s0;
      *(uint32_t*)(code + (size_t)t * NHu + codeoff) = cword;
    }
  }
}

// step_d: pure byte logic. 4 active px/thread; accept <=> dadh+5 <= nibble.
// Full-u64 writeback is race-safe: concurrent readers only use passive-parity
// bytes, whose values are bit-identical before/after the store.
template <int LAST>
__global__ __launch_bounds__(256) void step_d(uint8_t* __restrict__ ids,
                                              const uint8_t* __restrict__ codeT,
                                              float* __restrict__ out,
                                              int subi) {
  uint32_t n   = blockIdx.x * 256u + (uint32_t)threadIdx.x;  // 0 .. 2^20-1
  uint32_t sub = (uint32_t)subi;
  uint32_t b   = n >> 17;
  uint32_t y   = (n >> 7) & 1023u;
  uint32_t c   = (y + sub) & 1u;
  uint32_t X8  = (n & 127u) << 3;
  uint32_t rowp = (b << 20) | (y << 10);
  uint32_t upp  = (b << 20) | (((y + 1u) & 1023u) << 10);
  uint32_t dnp  = (b << 20) | (((y - 1u) & 1023u) << 10);

  uint32_t cw = *(const uint32_t*)(codeT + ((b << 19) | (y << 9) | ((n & 127u) << 2)));

  uint64_t mid = *(const uint64_t*)(ids + rowp + X8);
  uint64_t up  = *(const uint64_t*)(ids + upp + X8);
  uint64_t dn  = *(const uint64_t*)(ids + dnp + X8);
  uint32_t e   = c ? (uint32_t)ids[rowp + ((X8 + 8u) & 1023u)]
                   : (uint32_t)ids[rowp + ((X8 + 1023u) & 1023u)];

  uint32_t nw[4];
#pragma unroll
  for (int k = 0; k < 4; k++) {
    uint32_t self  = c ? BY(mid, 2 * k + 1) : BY(mid, 2 * k);
    uint32_t left  = c ? BY(mid, 2 * k)
                       : ((k == 0) ? e : BY(mid, 2 * k - 1));
    uint32_t right = c ? ((k == 3) ? e : BY(mid, 2 * k + 2))
                       : BY(mid, 2 * k + 1);
    uint32_t n0 = c ? BY(up, 2 * k + 1) : BY(up, 2 * k);   // roll(-1,0): y+1
    uint32_t n1 = c ? BY(dn, 2 * k + 1) : BY(dn, 2 * k);   // roll(+1,0): y-1

    uint32_t bk  = (cw >> (8 * k)) & 0xffu;
    uint32_t dir = (bk >> 4) & 3u;
    uint32_t ds5 = bk & 15u;
    uint32_t s  = (dir == 0) ? n0 : (dir == 1) ? n1 : (dir == 2) ? right : left;
    int dadh = ((int)(n0 != s) + (int)(n1 != s) + (int)(right != s) + (int)(left != s))
             - ((int)(n0 != self) + (int)(n1 != self) + (int)(right != self) + (int)(left != self));
    nw[k] = ((uint32_t)(dadh + 5) <= ds5) ? s : self;
  }

  if (!LAST) {
    uint64_t A = (uint64_t)nw[0] | ((uint64_t)nw[1] << 16)
               | ((uint64_t)nw[2] << 32) | ((uint64_t)nw[3] << 48);
    uint64_t mask = 0x00FF00FF00FF00FFull << (8u * c);
    uint64_t nm = (mid & ~mask) | (A << (8u * c));
    *(uint64_t*)(ids + rowp + X8) = nm;
  } else {
    float f[8];
#pragma unroll
    for (int j = 0; j < 8; j++) {
      uint32_t bj = (((uint32_t)j & 1u) == c) ? nw[j >> 1] : BY(mid, j);
      f[j] = (float)bj;
    }
    float4 f0 = {f[0], f[1], f[2], f[3]};
    float4 f1 = {f[4], f[5], f[6], f[7]};
    float* op = out + ((size_t)b << 23) + (y << 10) + X8;
    *(float4*)op       = f0;
    *(float4*)(op + 4) = f1;
  }
}

// ----------------------------------------------- fallback (small-ws) kernels
__device__ __forceinline__ void metro_one(uint32_t u, uint32_t sub,
                                          uint8_t* __restrict__ ids,
                                          const float* __restrict__ dHNN,
                                          uint32_t dk0, uint32_t dk1,
                                          uint32_t uk0, uint32_t uk1) {
  uint32_t b = u >> 19;
  uint32_t r = u & 524287u;
  uint32_t y = r >> 9;
  uint32_t i = r & 511u;
  uint32_t x = (i << 1) | ((y + sub) & 1u);
  uint32_t p = (b << 20) | (y << 10) | x;
  float4 dnn = ((const float4*)dHNN)[sub * NHu + u];
  uint32_t d0, d1, u0, u1;
  tf2x32(dk0, dk1, 0u, p, d0, d1);
  uint32_t db = d0 ^ d1;
  tf2x32(uk0, uk1, 0u, p, u0, u1);
  uint32_t ub = u0 ^ u1;
  int   dir = (int)(db & 3u);
  float uu  = __fsub_rn(__uint_as_float((ub >> 9) | 0x3F800000u), 1.0f);
  uint32_t yN = (y + 1) & 1023u, yP = (y - 1) & 1023u;
  uint32_t xN = (x + 1) & 1023u, xP = (x - 1) & 1023u;
  uint32_t base = b << 20;
  uint32_t cc = ids[p];
  uint32_t n0 = ids[base + (yN << 10) + x];
  uint32_t n1 = ids[base + (yP << 10) + x];
  uint32_t n2 = ids[base + (y << 10) + xN];
  uint32_t n3 = ids[base + (y << 10) + xP];
  uint32_t s  = (dir == 0) ? n0 : (dir == 1) ? n1 : (dir == 2) ? n2 : n3;
  float dH_nn = (dir == 0) ? dnn.x : (dir == 1) ? dnn.y : (dir == 2) ? dnn.z : dnn.w;
  int dadh = ((int)(n0 != s) + (int)(n1 != s) + (int)(n2 != s) + (int)(n3 != s))
           - ((int)(n0 != cc) + (int)(n1 != cc) + (int)(n2 != cc) + (int)(n3 != cc));
  float dH = __fadd_rn((float)dadh, dH_nn);
  if (uu < xla_expf(-dH)) ids[p] = (uint8_t)s;
}

__global__ __launch_bounds__(256) void prep4_fb(const float* __restrict__ X,
                                                const float* __restrict__ W,
                                                const float* __restrict__ Bb,
                                                float* __restrict__ dHNN,
                                                uint8_t* __restrict__ ids) {
  int tid = blockIdx.x * 256 + threadIdx.x;
  int e   = tid << 2;
  int b   = e >> 20;
  int yx  = e & (HW - 1);
  int y   = yx >> 10;
  int x0  = yx & 1023;
  int q4  = yx >> 2;
  const float4* xb = (const float4*)(X + ((size_t)b << 23));
  float4 xc[8];
#pragma unroll
  for (int c = 0; c < 8; c++) xc[c] = xb[(c << 18) + q4];
#pragma unroll
  for (int j = 0; j < 4; j++) {
    float4 r;
#pragma unroll
    for (int o = 0; o < 4; o++) {
      float acc = 0.0f;
#pragma unroll
      for (int c = 0; c < 8; c++)
        acc = __fadd_rn(acc, __fmul_rn(((const float*)&xc[c])[j], W[o * 8 + c]));
      ((float*)&r)[o] = __fadd_rn(acc, Bb[o]);
    }
    int xj = x0 + j;
    ((float4*)dHNN)[((xj + y) & 1) * NHu + (uint32_t)((b << 19) | (y << 9) | (xj >> 1))] = r;
  }
  uchar4 v;
  v.x = (uint8_t)(int)xc[0].x; v.y = (uint8_t)(int)xc[0].y;
  v.z = (uint8_t)(int)xc[0].z; v.w = (uint8_t)(int)xc[0].w;
  *(uchar4*)(ids + e) = v;
}

__global__ __launch_bounds__(256) void half_step_fb(uint8_t* __restrict__ ids,
                                                    const float* __restrict__ dHNN,
                                                    uint32_t dk0, uint32_t dk1,
                                                    uint32_t uk0, uint32_t uk1,
                                                    int sub) {
  uint32_t u = blockIdx.x * 256u + threadIdx.x;
  metro_one(u, (uint32_t)sub, ids, dHNN, dk0, dk1, uk0, uk1);
}

__global__ __launch_bounds__(256) void finalize_full_fb(const float* __restrict__ X,
                                                        const uint8_t* __restrict__ ids,
                                                        float* __restrict__ out) {
  int t = blockIdx.x * 256 + threadIdx.x;
  int e = t << 2;
  int c = (e >> 20) & 7;
  float4 r;
  if (c == 0) {
    int b  = e >> 23;
    int yx = e & (HW - 1);
    uchar4 v = *(const uchar4*)(ids + ((size_t)b << 20) + yx);
    r.x = (float)v.x; r.y = (float)v.y; r.z = (float)v.z; r.w = (float)v.w;
  } else {
    r = ((const float4*)X)[t];
  }
  ((float4*)out)[t] = r;
}

// --------------------------------------------------------------------- host
extern "C" void kernel_launch(void* const* d_in, const int* in_sizes, int n_in,
                              void* d_out, int out_size, void* d_ws, size_t ws_size,
                              hipStream_t stream) {
  const float* X  = (const float*)d_in[0];
  const float* W  = (const float*)d_in[1];
  const float* Bb = (const float*)d_in[2];
  float* out = (float*)d_out;

  const size_t CODE_BYTES = (size_t)NHu * 8u;    // 33.5 MB (8 planes)
  const size_t IDS_BYTES  = (size_t)BHWu;        // 8.4 MB

  // Threefry key chain (partitionable stream; verified rounds 2-7).
  uint32_t bk0 = 0u, bk1 = 42u;
  uint32_t keys[8][2];
  for (uint32_t t = 0; t < 8; t++)
    tf2x32(bk0, bk1, 0u, t, keys[t][0], keys[t][1]);
  uint32_t K[8][4];
  KeysK KK;
  for (int t = 0; t < 8; t++) {
    uint32_t k1a, k1b;
    tf2x32(keys[t][0], keys[t][1], 0u, 0u, k1a, k1b);         // k1 (randint arg)
    tf2x32(keys[t][0], keys[t][1], 0u, 1u, K[t][2], K[t][3]); // k2 -> ukey
    tf2x32(k1a, k1b, 0u, 1u, K[t][0], K[t][1]);               // randint kk2 -> dkey
    KK.d[t][0] = K[t][0]; KK.d[t][1] = K[t][1];
    KK.u[t][0] = K[t][2]; KK.u[t][1] = K[t][3];
  }

  bool ws_ok = ws_size >= CODE_BYTES + IDS_BYTES;
  if (ws_ok) {
    uint8_t* code = (uint8_t*)d_ws;
    uint8_t* ids  = (uint8_t*)d_ws + CODE_BYTES;

    prep_fused<<<7680, 256, 0, stream>>>(X, W, Bb, code, ids, out, KK);
    for (int t = 0; t < 7; t++)
      step_d<0><<<4096, 256, 0, stream>>>(ids, code + (size_t)t * NHu, out, t & 1);
    step_d<1><<<4096, 256, 0, stream>>>(ids, code + (size_t)7 * NHu, out, 1);
  } else {
    float*   dHNN = out;                 // dHNN lives in out; ids in ws
    uint8_t* ids  = (uint8_t*)d_ws;
    prep4_fb<<<8192, 256, 0, stream>>>(X, W, Bb, dHNN, ids);
    for (int t = 0; t < 8; t++)
      half_step_fb<<<16384, 256, 0, stream>>>(ids, dHNN,
          K[t][0], K[t][1], K[t][2], K[t][3], t & 1);
    finalize_full_fb<<<65536, 256, 0, stream>>>(X, ids, out);
  }
  (void)in_sizes; (void)n_in; (void)out_size;
}

// Round 9
// 262.374 us; speedup vs baseline: 7.8294x; 1.1134x over previous
//
#include <hip/hip_runtime.h>
#include <stdint.h>

// ============================================================================
// CPM layer, bit-exact JAX reproduction. B=8, C=8, H=W=1024.
// Round 9: decision code via CERTAINTY-BAND threshold guess:
//   tau = -v - ln(u)  (v_log_f32 hardware log2, err <= ~2e-6 in tau units)
//   d* = floor(tau) certainly, unless frac(tau) within 1e-4 of {0,1} ->
//   resolve with ONE exact Cephes eval (band has 30x margin over total err;
//   argument needs only |C/exp - 1| <= 1e-5, no monotonicity).
//   u==0 (possible, ~4 px/step) -> d*=4 (exp>0 always).
// Replaces round-8's 4 Cephes evals/px-step (~27% of prep VALU) with ~0.
// Steps remain pure byte logic. RNG / dot / exact-exp exprs bit-identical.
// ============================================================================

#define HW    1048576    // 1024*1024
#define BHWu  8388608u   // 8*HW
#define NHu   4194304u   // BHW/2 = packed entries per parity (code plane bytes)

struct KeysK { uint32_t d[8][2]; uint32_t u[8][2]; };

// ---------------------------------------------------------------------- RNG
__device__ __host__ __forceinline__ void tf2x32(uint32_t k0, uint32_t k1,
                                                uint32_t x0, uint32_t x1,
                                                uint32_t& o0, uint32_t& o1) {
  uint32_t k2 = k0 ^ k1 ^ 0x1BD11BDAu;
  x0 += k0; x1 += k1;
#define RDD(r) { x0 += x1; x1 = (x1 << (r)) | (x1 >> (32 - (r))); x1 ^= x0; }
  RDD(13) RDD(15) RDD(26) RDD(6)
  x0 += k1; x1 += k2 + 1u;
  RDD(17) RDD(29) RDD(16) RDD(24)
  x0 += k2; x1 += k0 + 2u;
  RDD(13) RDD(15) RDD(26) RDD(6)
  x0 += k0; x1 += k1 + 3u;
  RDD(17) RDD(29) RDD(16) RDD(24)
  x0 += k1; x1 += k2 + 4u;
  RDD(13) RDD(15) RDD(26) RDD(6)
  x0 += k2; x1 += k0 + 5u;
#undef RDD
  o0 = x0; o1 = x1;
}

// ------------------------------------------------- XLA-CPU Cephes expf clone
__device__ __forceinline__ float xla_expf(float input) {
  float x  = fmaxf(fminf(input, 88.3762626647950f), -88.3762626647949f);
  float fx = floorf(fmaf(x, 1.44269504088896341f, 0.5f));
  float tmp = __fmul_rn(0.693359375f, fx);
  float z   = __fmul_rn(-2.12194440e-4f, fx);
  x = __fsub_rn(x, tmp);
  x = __fsub_rn(x, z);
  z = __fmul_rn(x, x);
  float y = fmaf(x, 1.9875691500e-4f, 1.3981999507e-3f);
  y = fmaf(y, x, 8.3334519073e-3f);
  y = fmaf(y, x, 4.1665795894e-2f);
  y = fmaf(y, x, 1.6666665459e-1f);
  y = fmaf(y, x, 5.0000001201e-1f);
  y = fmaf(y, z, x);
  y = __fadd_rn(y, 1.0f);
  int n = (int)fx;
  float p2n = __int_as_float((n + 127) << 23);
  return fmaxf(__fmul_rn(y, p2n), input);
}

#define BY(v, i) ((uint32_t)(((v) >> ((i) * 8)) & 0xffu))
// bit-exact accept predicate at integer d (same expr as the step's exp(-dH))
#define ACC_D(dd) (u < xla_expf(-__fadd_rn((float)(dd), v)))

// ------------------------------------------------------------------- kernels
// prep_fused: groups of 15 blocks = 8 compute + 7 copy.
__global__ __launch_bounds__(256) void prep_fused(const float* __restrict__ X,
                                                  const float* __restrict__ W,
                                                  const float* __restrict__ Bb,
                                                  uint8_t* __restrict__ code,
                                                  uint8_t* __restrict__ ids,
                                                  float* __restrict__ out,
                                                  KeysK K) {
  const uint32_t tid = threadIdx.x;
  const uint32_t g = blockIdx.x, group = g / 15u, r = g - group * 15u;
  if (r >= 8u) {                              // ---- copy role (ch1-7)
    uint32_t j = group * 7u + (r - 8u);       // 0..3583
    const float4* X4 = (const float4*)X;
    float4*       O4 = (float4*)out;
#pragma unroll
    for (uint32_t i = 0; i < 16u; i++) {
      uint32_t F = j * 4096u + i * 256u + tid;
      uint32_t b = F / 1835008u;
      uint32_t rem = F - b * 1835008u;
      size_t idx = ((size_t)b << 21) + 262144u + rem;  // b*2^21 + ch1 offset
      O4[idx] = X4[idx];
    }
    return;
  }
  // ---- compute role
  const uint32_t cb    = group * 8u + r;      // 0..4095
  const uint32_t lane  = tid & 127u;
  const uint32_t rhalf = tid >> 7;
  const uint32_t row   = cb * 2u + rhalf;     // 0..8191
  const uint32_t b = row >> 10, y = row & 1023u;
  const uint32_t ylsb = y & 1u;

  const float4* xb = (const float4*)(X + ((size_t)b << 23));
  const uint32_t fq = (y << 8) + 2u * lane;

  float acc[8][4];
  float x0[8];
#pragma unroll
  for (int c = 0; c < 8; c++) {
    float4 a  = xb[((uint32_t)c << 18) + fq];
    float4 bv = xb[((uint32_t)c << 18) + fq + 1u];
    float xs[8] = {a.x, a.y, a.z, a.w, bv.x, bv.y, bv.z, bv.w};
    if (c == 0) {
#pragma unroll
      for (int px = 0; px < 8; px++) x0[px] = xs[px];
    }
#pragma unroll
    for (int px = 0; px < 8; px++)
#pragma unroll
      for (int o = 0; o < 4; o++) {
        float m = __fmul_rn(xs[px], W[o * 8 + c]);
        acc[px][o] = (c == 0) ? __fadd_rn(0.0f, m) : __fadd_rn(acc[px][o], m);
      }
  }
#pragma unroll
  for (int px = 0; px < 8; px++)
#pragma unroll
    for (int o = 0; o < 4; o++) acc[px][o] = __fadd_rn(acc[px][o], Bb[o]);

  {  // ids: 8 bytes packed
    uint32_t lo = ((uint32_t)(uint8_t)(int)x0[0])
                | ((uint32_t)(uint8_t)(int)x0[1] << 8)
                | ((uint32_t)(uint8_t)(int)x0[2] << 16)
                | ((uint32_t)(uint8_t)(int)x0[3] << 24);
    uint32_t hi = ((uint32_t)(uint8_t)(int)x0[4])
                | ((uint32_t)(uint8_t)(int)x0[5] << 8)
                | ((uint32_t)(uint8_t)(int)x0[6] << 16)
                | ((uint32_t)(uint8_t)(int)x0[7] << 24);
    uint2 v2 = {lo, hi};
    *(uint2*)(ids + (b << 20) + (y << 10) + 8u * lane) = v2;
  }

  const uint32_t pbase   = (b << 20) | (y << 10);
  const uint32_t codeoff = (b << 19) | (y << 9) | (4u * lane);
#pragma unroll
  for (int js = 0; js < 4; js++) {
#pragma unroll
    for (int pb = 0; pb < 2; pb++) {
      uint32_t s0 = ylsb ^ (uint32_t)pb;      // step t = 2*js + s0
      uint32_t dka = s0 ? K.d[2 * js + 1][0] : K.d[2 * js][0];
      uint32_t dkb = s0 ? K.d[2 * js + 1][1] : K.d[2 * js][1];
      uint32_t uka = s0 ? K.u[2 * js + 1][0] : K.u[2 * js][0];
      uint32_t ukb = s0 ? K.u[2 * js + 1][1] : K.u[2 * js][1];
      uint32_t cword = 0;
#pragma unroll
      for (int k = 0; k < 4; k++) {
        int px = 2 * k + pb;
        uint32_t p = pbase | (8u * lane + (uint32_t)px);
        uint32_t o0, o1, q0, q1;
        tf2x32(dka, dkb, 0u, p, o0, o1);
        uint32_t dir = (o0 ^ o1) & 3u;
        tf2x32(uka, ukb, 0u, p, q0, q1);
        uint32_t ub = (q0 ^ q1) >> 9;
        float u = __fsub_rn(__uint_as_float(ub | 0x3F800000u), 1.0f);
        float v = (dir == 0) ? acc[px][0] : (dir == 1) ? acc[px][1]
                : (dir == 2) ? acc[px][2] : acc[px][3];
        int dstar;
        if (ub == 0u) {                       // u == 0: always accept
          dstar = 4;
        } else {
          // tau = -v - ln(u); total err < ~3e-6 in tau units; band = 1e-4.
          float l2  = __log2f(u);             // v_log_f32
          float tau = fmaf(-0.693147180559945f, l2, -v);
          float gf  = floorf(tau);
          float fr  = tau - gf;
          int   gi  = (int)fmaxf(fminf(gf, 6.0f), -7.0f);
          dstar = gi;
          if (fr < 1e-4f)        dstar = ACC_D(gi)     ? gi     : gi - 1;
          else if (fr > 0.9999f) dstar = ACC_D(gi + 1) ? gi + 1 : gi;
        }
        dstar = dstar < -5 ? -5 : (dstar > 4 ? 4 : dstar);
        cword |= (uint32_t)((uint32_t)(dstar + 5) | (dir << 4)) << (8 * k);
      }
      uint32_t t = 2u * (uint32_t)js + s0;
      *(uint32_t*)(code + (size_t)t * NHu + codeoff) = cword;
    }
  }
}

// step_d: pure byte logic. 4 active px/thread; accept <=> dadh+5 <= nibble.
template <int LAST>
__global__ __launch_bounds__(256) void step_d(uint8_t* __restrict__ ids,
                                              const uint8_t* __restrict__ codeT,
                                              float* __restrict__ out,
                                              int subi) {
  uint32_t n   = blockIdx.x * 256u + (uint32_t)threadIdx.x;  // 0 .. 2^20-1
  uint32_t sub = (uint32_t)subi;
  uint32_t b   = n >> 17;
  uint32_t y   = (n >> 7) & 1023u;
  uint32_t c   = (y + sub) & 1u;
  uint32_t X8  = (n & 127u) << 3;
  uint32_t rowp = (b << 20) | (y << 10);
  uint32_t upp  = (b << 20) | (((y + 1u) & 1023u) << 10);
  uint32_t dnp  = (b << 20) | (((y - 1u) & 1023u) << 10);

  uint32_t cw = *(const uint32_t*)(codeT + ((b << 19) | (y << 9) | ((n & 127u) << 2)));

  uint64_t mid = *(const uint64_t*)(ids + rowp + X8);
  uint64_t up  = *(const uint64_t*)(ids + upp + X8);
  uint64_t dn  = *(const uint64_t*)(ids + dnp + X8);
  uint32_t e   = c ? (uint32_t)ids[rowp + ((X8 + 8u) & 1023u)]
                   : (uint32_t)ids[rowp + ((X8 + 1023u) & 1023u)];

  uint32_t nw[4];
#pragma unroll
  for (int k = 0; k < 4; k++) {
    uint32_t self  = c ? BY(mid, 2 * k + 1) : BY(mid, 2 * k);
    uint32_t left  = c ? BY(mid, 2 * k)
                       : ((k == 0) ? e : BY(mid, 2 * k - 1));
    uint32_t right = c ? ((k == 3) ? e : BY(mid, 2 * k + 2))
                       : BY(mid, 2 * k + 1);
    uint32_t n0 = c ? BY(up, 2 * k + 1) : BY(up, 2 * k);   // roll(-1,0): y+1
    uint32_t n1 = c ? BY(dn, 2 * k + 1) : BY(dn, 2 * k);   // roll(+1,0): y-1

    uint32_t bk  = (cw >> (8 * k)) & 0xffu;
    uint32_t dir = (bk >> 4) & 3u;
    uint32_t ds5 = bk & 15u;
    uint32_t s  = (dir == 0) ? n0 : (dir == 1) ? n1 : (dir == 2) ? right : left;
    int dadh = ((int)(n0 != s) + (int)(n1 != s) + (int)(right != s) + (int)(left != s))
             - ((int)(n0 != self) + (int)(n1 != self) + (int)(right != self) + (int)(left != self));
    nw[k] = ((uint32_t)(dadh + 5) <= ds5) ? s : self;
  }

  if (!LAST) {
    uint64_t A = (uint64_t)nw[0] | ((uint64_t)nw[1] << 16)
               | ((uint64_t)nw[2] << 32) | ((uint64_t)nw[3] << 48);
    uint64_t mask = 0x00FF00FF00FF00FFull << (8u * c);
    uint64_t nm = (mid & ~mask) | (A << (8u * c));
    *(uint64_t*)(ids + rowp + X8) = nm;
  } else {
    float f[8];
#pragma unroll
    for (int j = 0; j < 8; j++) {
      uint32_t bj = (((uint32_t)j & 1u) == c) ? nw[j >> 1] : BY(mid, j);
      f[j] = (float)bj;
    }
    float4 f0 = {f[0], f[1], f[2], f[3]};
    float4 f1 = {f[4], f[5], f[6], f[7]};
    float* op = out + ((size_t)b << 23) + (y << 10) + X8;
    *(float4*)op       = f0;
    *(float4*)(op + 4) = f1;
  }
}

// ----------------------------------------------- fallback (small-ws) kernels
__device__ __forceinline__ void metro_one(uint32_t u, uint32_t sub,
                                          uint8_t* __restrict__ ids,
                                          const float* __restrict__ dHNN,
                                          uint32_t dk0, uint32_t dk1,
                                          uint32_t uk0, uint32_t uk1) {
  uint32_t b = u >> 19;
  uint32_t r = u & 524287u;
  uint32_t y = r >> 9;
  uint32_t i = r & 511u;
  uint32_t x = (i << 1) | ((y + sub) & 1u);
  uint32_t p = (b << 20) | (y << 10) | x;
  float4 dnn = ((const float4*)dHNN)[sub * NHu + u];
  uint32_t d0, d1, u0, u1;
  tf2x32(dk0, dk1, 0u, p, d0, d1);
  uint32_t db = d0 ^ d1;
  tf2x32(uk0, uk1, 0u, p, u0, u1);
  uint32_t ub = u0 ^ u1;
  int   dir = (int)(db & 3u);
  float uu  = __fsub_rn(__uint_as_float((ub >> 9) | 0x3F800000u), 1.0f);
  uint32_t yN = (y + 1) & 1023u, yP = (y - 1) & 1023u;
  uint32_t xN = (x + 1) & 1023u, xP = (x - 1) & 1023u;
  uint32_t base = b << 20;
  uint32_t cc = ids[p];
  uint32_t n0 = ids[base + (yN << 10) + x];
  uint32_t n1 = ids[base + (yP << 10) + x];
  uint32_t n2 = ids[base + (y << 10) + xN];
  uint32_t n3 = ids[base + (y << 10) + xP];
  uint32_t s  = (dir == 0) ? n0 : (dir == 1) ? n1 : (dir == 2) ? n2 : n3;
  float dH_nn = (dir == 0) ? dnn.x : (dir == 1) ? dnn.y : (dir == 2) ? dnn.z : dnn.w;
  int dadh = ((int)(n0 != s) + (int)(n1 != s) + (int)(n2 != s) + (int)(n3 != s))
           - ((int)(n0 != cc) + (int)(n1 != cc) + (int)(n2 != cc) + (int)(n3 != cc));
  float dH = __fadd_rn((float)dadh, dH_nn);
  if (uu < xla_expf(-dH)) ids[p] = (uint8_t)s;
}

__global__ __launch_bounds__(256) void prep4_fb(const float* __restrict__ X,
                                                const float* __restrict__ W,
                                                const float* __restrict__ Bb,
                                                float* __restrict__ dHNN,
                                                uint8_t* __restrict__ ids) {
  int tid = blockIdx.x * 256 + threadIdx.x;
  int e   = tid << 2;
  int b   = e >> 20;
  int yx  = e & (HW - 1);
  int y   = yx >> 10;
  int x0  = yx & 1023;
  int q4  = yx >> 2;
  const float4* xb = (const float4*)(X + ((size_t)b << 23));
  float4 xc[8];
#pragma unroll
  for (int c = 0; c < 8; c++) xc[c] = xb[(c << 18) + q4];
#pragma unroll
  for (int j = 0; j < 4; j++) {
    float4 r;
#pragma unroll
    for (int o = 0; o < 4; o++) {
      float acc = 0.0f;
#pragma unroll
      for (int c = 0; c < 8; c++)
        acc = __fadd_rn(acc, __fmul_rn(((const float*)&xc[c])[j], W[o * 8 + c]));
      ((float*)&r)[o] = __fadd_rn(acc, Bb[o]);
    }
    int xj = x0 + j;
    ((float4*)dHNN)[((xj + y) & 1) * NHu + (uint32_t)((b << 19) | (y << 9) | (xj >> 1))] = r;
  }
  uchar4 v;
  v.x = (uint8_t)(int)xc[0].x; v.y = (uint8_t)(int)xc[0].y;
  v.z = (uint8_t)(int)xc[0].z; v.w = (uint8_t)(int)xc[0].w;
  *(uchar4*)(ids + e) = v;
}

__global__ __launch_bounds__(256) void half_step_fb(uint8_t* __restrict__ ids,
                                                    const float* __restrict__ dHNN,
                                                    uint32_t dk0, uint32_t dk1,
                                                    uint32_t uk0, uint32_t uk1,
                                                    int sub) {
  uint32_t u = blockIdx.x * 256u + threadIdx.x;
  metro_one(u, (uint32_t)sub, ids, dHNN, dk0, dk1, uk0, uk1);
}

__global__ __launch_bounds__(256) void finalize_full_fb(const float* __restrict__ X,
                                                        const uint8_t* __restrict__ ids,
                                                        float* __restrict__ out) {
  int t = blockIdx.x * 256 + threadIdx.x;
  int e = t << 2;
  int c = (e >> 20) & 7;
  float4 r;
  if (c == 0) {
    int b  = e >> 23;
    int yx = e & (HW - 1);
    uchar4 v = *(const uchar4*)(ids + ((size_t)b << 20) + yx);
    r.x = (float)v.x; r.y = (float)v.y; r.z = (float)v.z; r.w = (float)v.w;
  } else {
    r = ((const float4*)X)[t];
  }
  ((float4*)out)[t] = r;
}

// --------------------------------------------------------------------- host
extern "C" void kernel_launch(void* const* d_in, const int* in_sizes, int n_in,
                              void* d_out, int out_size, void* d_ws, size_t ws_size,
                              hipStream_t stream) {
  const float* X  = (const float*)d_in[0];
  const float* W  = (const float*)d_in[1];
  const float* Bb = (const float*)d_in[2];
  float* out = (float*)d_out;

  const size_t CODE_BYTES = (size_t)NHu * 8u;    // 33.5 MB (8 planes)
  const size_t IDS_BYTES  = (size_t)BHWu;        // 8.4 MB

  // Threefry key chain (partitionable stream; verified rounds 2-8).
  uint32_t bk0 = 0u, bk1 = 42u;
  uint32_t keys[8][2];
  for (uint32_t t = 0; t < 8; t++)
    tf2x32(bk0, bk1, 0u, t, keys[t][0], keys[t][1]);
  uint32_t K[8][4];
  KeysK KK;
  for (int t = 0; t < 8; t++) {
    uint32_t k1a, k1b;
    tf2x32(keys[t][0], keys[t][1], 0u, 0u, k1a, k1b);         // k1 (randint arg)
    tf2x32(keys[t][0], keys[t][1], 0u, 1u, K[t][2], K[t][3]); // k2 -> ukey
    tf2x32(k1a, k1b, 0u, 1u, K[t][0], K[t][1]);               // randint kk2 -> dkey
    KK.d[t][0] = K[t][0]; KK.d[t][1] = K[t][1];
    KK.u[t][0] = K[t][2]; KK.u[t][1] = K[t][3];
  }

  bool ws_ok = ws_size >= CODE_BYTES + IDS_BYTES;
  if (ws_ok) {
    uint8_t* code = (uint8_t*)d_ws;
    uint8_t* ids  = (uint8_t*)d_ws + CODE_BYTES;

    prep_fused<<<7680, 256, 0, stream>>>(X, W, Bb, code, ids, out, KK);
    for (int t = 0; t < 7; t++)
      step_d<0><<<4096, 256, 0, stream>>>(ids, code + (size_t)t * NHu, out, t & 1);
    step_d<1><<<4096, 256, 0, stream>>>(ids, code + (size_t)7 * NHu, out, 1);
  } else {
    float*   dHNN = out;                 // dHNN lives in out; ids in ws
    uint8_t* ids  = (uint8_t*)d_ws;
    prep4_fb<<<8192, 256, 0, stream>>>(X, W, Bb, dHNN, ids);
    for (int t = 0; t < 8; t++)
      half_step_fb<<<16384, 256, 0, stream>>>(ids, dHNN,
          K[t][0], K[t][1], K[t][2], K[t][3], t & 1);
    finalize_full_fb<<<65536, 256, 0, stream>>>(X, ids, out);
  }
  (void)in_sizes; (void)n_in; (void)out_size;
}